// Round 1
// baseline (173.724 us; speedup 1.0000x reference)
//
#include <hip/hip_runtime.h>
#include <stdint.h>

#define NB 16
#define NN 2048
#define ND 128
#define NH 32
#define NS (NB*NN)

typedef __attribute__((ext_vector_type(8))) short bf16x8;
typedef __attribute__((ext_vector_type(4))) float f32x4;

__device__ __forceinline__ unsigned short f2bf(float f){
  union { float f; unsigned int u; } v; v.f = f;
  unsigned int r = v.u + 0x7fffu + ((v.u >> 16) & 1u);
  return (unsigned short)(r >> 16);
}
__device__ __forceinline__ float bf2f(unsigned short u){
  union { unsigned int u; float f; } v; v.u = ((unsigned int)u) << 16;
  return v.f;
}

// ---------------- k_prep: fp32 weights -> bf16 ----------------
__global__ __launch_bounds__(256) void k_prep(const float* wq, const float* wk, const float* wv, const float* wl,
                                              unsigned short* oq, unsigned short* ok, unsigned short* ov, unsigned short* ol){
  int i = blockIdx.x*256 + threadIdx.x;
  if (i < 4096) oq[i] = f2bf(wq[i]);
  else if (i < 8192) ok[i-4096] = f2bf(wk[i-4096]);
  else if (i < 24576) ov[i-8192] = f2bf(wv[i-8192]);
  else if (i < 40960) ol[i-24576] = f2bf(wl[i-24576]);
}

// ---------------- k_qkv: Q,K (S x 32), V (S x 128) in bf16 ----------------
// MFMA 16x16x32: A lane l holds A[l&15][8*(l>>4)+j]; B lane l holds B[8*(l>>4)+j][l&15];
// C lane l reg r holds C[4*(l>>4)+r][l&15]  (m89-verified C/D mapping)
__global__ __launch_bounds__(256) void k_qkv(const float* f, const unsigned short* wbq, const unsigned short* wbk,
                                             const unsigned short* wbv, const float* bq, const float* bk, const float* bv,
                                             unsigned short* Qb, unsigned short* Kb, unsigned short* Vb){
  int tid = threadIdx.x, wave = tid>>6, lane = tid&63, lr = lane&15, lg = lane>>4;
  long r0 = (long)blockIdx.x*64 + wave*16;
  bf16x8 a[4];
  const float* frow = f + (r0 + lr)*ND;
  #pragma unroll
  for (int ks=0; ks<4; ks++){
    const float* p = frow + ks*32 + lg*8;
    bf16x8 t;
    #pragma unroll
    for (int j=0;j<8;j++) t[j] = (short)f2bf(p[j]);
    a[ks] = t;
  }
  #pragma unroll
  for (int cs=0; cs<12; cs++){
    const unsigned short* wsrc; const float* bsrc; int cl;
    if (cs<2){ wsrc=wbq; bsrc=bq; cl=cs*16; }
    else if (cs<4){ wsrc=wbk; bsrc=bk; cl=(cs-2)*16; }
    else { wsrc=wbv; bsrc=bv; cl=(cs-4)*16; }
    f32x4 acc = {0.f,0.f,0.f,0.f};
    #pragma unroll
    for (int ks=0;ks<4;ks++){
      bf16x8 b = *(const bf16x8*)(wsrc + (cl+lr)*ND + ks*32 + lg*8);
      acc = __builtin_amdgcn_mfma_f32_16x16x32_bf16(a[ks], b, acc, 0, 0, 0);
    }
    float bias = bsrc[cl + lr];
    #pragma unroll
    for (int r=0;r<4;r++){
      float v = acc[r] + bias;
      long row = r0 + lg*4 + r;
      if (cs<2) Qb[row*NH + cl+lr] = f2bf(v);
      else if (cs<4) Kb[row*NH + cl+lr] = f2bf(v);
      else Vb[row*ND + cl+lr] = f2bf(v);
    }
  }
}

// ---------------- k_colsum: wrcp[b][m] = 1 / sum_n exp(q_n . k_m) ----------------
__global__ __launch_bounds__(256) void k_colsum(const unsigned short* Qb, const unsigned short* Kb, float* wrcp){
  int tid=threadIdx.x, wave=tid>>6, lane=tid&63, lr=lane&15, lg=lane>>4;
  int b = blockIdx.x >> 5;
  int m0 = (blockIdx.x & 31)*64 + wave*16;
  const unsigned short* Qbb = Qb + (long)b*NN*NH;
  const unsigned short* Kbb = Kb + (long)b*NN*NH;
  bf16x8 kf = *(const bf16x8*)(Kbb + (m0+lr)*NH + lg*8);
  float csum = 0.f;
  for (int n0=0; n0<NN; n0+=64){
    #pragma unroll
    for (int u=0; u<4; u++){
      bf16x8 qf = *(const bf16x8*)(Qbb + (n0+u*16+lr)*NH + lg*8);
      f32x4 c = {0.f,0.f,0.f,0.f};
      c = __builtin_amdgcn_mfma_f32_16x16x32_bf16(qf, kf, c, 0, 0, 0);
      csum += __expf(c[0]) + __expf(c[1]) + __expf(c[2]) + __expf(c[3]);
    }
  }
  csum += __shfl_xor(csum, 16, 64);
  csum += __shfl_xor(csum, 32, 64);
  if (lg == 0) wrcp[b*NN + m0 + lr] = 1.f / csum;
}

// ---------------- k_vprime: VT[b][e][m] = V[m][e]*w[m]; VT[b][128][m]=w[m]; rows 129..143 = 0 ----------------
__global__ __launch_bounds__(256) void k_vprime(const unsigned short* Vb, const float* wrcp, unsigned short* VT){
  __shared__ unsigned short tr[128][65];
  int tid = threadIdx.x;
  int b = blockIdx.x >> 5;
  int m0 = (blockIdx.x & 31)*64;
  const unsigned short* Vbb = Vb + ((long)b*NN + m0)*ND;
  #pragma unroll
  for (int it=0; it<4; it++){
    int i = it*256 + tid;          // 0..1023 : 64 rows x 16 vec8
    int r = i >> 4, c8 = (i & 15)*8;
    bf16x8 v = *(const bf16x8*)(Vbb + r*ND + c8);
    #pragma unroll
    for (int j=0;j<8;j++) tr[c8+j][r] = (unsigned short)v[j];
  }
  __syncthreads();
  unsigned short* VTb = VT + (long)b*144*NN;
  for (int it=0; it<36; it++){
    int i = it*256 + tid;          // 0..9215 : 144 rows x 64
    int e = i >> 6, ml = i & 63;
    float w = wrcp[b*NN + m0 + ml];
    unsigned short o;
    if (e < 128) o = f2bf(bf2f(tr[e][ml]) * w);
    else if (e == 128) o = f2bf(w);
    else o = 0;
    VTb[(long)e*NN + m0 + ml] = o;
  }
}

// ---------------- k_pv: f_sa = (E @ V') / (E @ w), E = exp(QK^T) recomputed in-register ----------------
__global__ __launch_bounds__(256) void k_pv(const unsigned short* Qb, const unsigned short* Kb,
                                            const unsigned short* VT, float* fsa){
  __shared__ __align__(16) unsigned char vts[144*128];   // [e][64 m], XOR-swizzled rows
  __shared__ __align__(16) unsigned char es[4][16*128];  // per-wave E tile [16 rows][64 m], swizzled
  __shared__ float rdl[4][16];
  int tid=threadIdx.x, wave=tid>>6, lane=tid&63, lr=lane&15, lg=lane>>4;
  int b = blockIdx.x >> 5;
  int nloc = (blockIdx.x & 31)*64 + wave*16;
  const unsigned short* Qbb = Qb + (long)b*NN*NH;
  const unsigned short* Kbb = Kb + (long)b*NN*NH;
  const unsigned short* VTb = VT + (long)b*144*NN;
  bf16x8 qf = *(const bf16x8*)(Qbb + (nloc+lr)*NH + lg*8);
  f32x4 acc[9];
  #pragma unroll
  for (int cs=0;cs<9;cs++) acc[cs] = (f32x4){0.f,0.f,0.f,0.f};

  for (int m0=0; m0<NN; m0+=64){
    // stage V'^T chunk [144][64] into LDS, swizzled: byte = e*128 + ((mm*2) ^ ((e&7)<<4))
    for (int i = tid; i < 1152; i += 256){
      int e = i >> 3, blk = i & 7;
      bf16x8 v = *(const bf16x8*)(VTb + (long)e*NN + m0 + blk*8);
      *(bf16x8*)(vts + e*128 + ((blk*16) ^ ((e&7)<<4))) = v;
    }
    // scores -> exp -> E tile in LDS (each wave its own 16 rows)
    #pragma unroll
    for (int s=0; s<4; s++){
      bf16x8 kf = *(const bf16x8*)(Kbb + (m0 + s*16 + lr)*NH + lg*8);
      f32x4 c = {0.f,0.f,0.f,0.f};
      c = __builtin_amdgcn_mfma_f32_16x16x32_bf16(qf, kf, c, 0, 0, 0);
      #pragma unroll
      for (int r=0;r<4;r++){
        int row = lg*4 + r;
        int col = s*16 + lr;
        unsigned short ev = f2bf(__expf(c[r]));
        *(unsigned short*)(es[wave] + row*128 + ((col*2) ^ ((row&7)<<4))) = ev;
      }
    }
    __syncthreads();
    // PV: acc[cs] += E(16x64) @ V'(64x144)
    #pragma unroll
    for (int ks=0; ks<2; ks++){
      bf16x8 ea = *(const bf16x8*)(es[wave] + lr*128 + (((ks*32 + lg*8)*2) ^ ((lr&7)<<4)));
      #pragma unroll
      for (int cs=0; cs<9; cs++){
        int e = cs*16 + lr;
        bf16x8 vb = *(const bf16x8*)(vts + e*128 + (((ks*32 + lg*8)*2) ^ ((e&7)<<4)));
        acc[cs] = __builtin_amdgcn_mfma_f32_16x16x32_bf16(ea, vb, acc[cs], 0, 0, 0);
      }
    }
    __syncthreads();
  }
  // rden lives in acc[8] at col-local 0 (e = 128)
  if (lr == 0){
    #pragma unroll
    for (int r=0;r<4;r++) rdl[wave][lg*4+r] = acc[8][r];
  }
  __syncthreads();
  long grow0 = (long)b*NN + nloc;
  #pragma unroll
  for (int r=0;r<4;r++){
    int row = lg*4 + r;
    float rinv = 1.f / rdl[wave][row];
    #pragma unroll
    for (int cs=0;cs<8;cs++){
      fsa[(grow0 + row)*ND + cs*16 + lr] = acc[cs][r] * rinv;
    }
  }
}

// ---------------- k_lin: y = (f - fsa) @ w_l^T + b_l -> ybuf(bf16); per-block channel partial sums ----------------
__global__ __launch_bounds__(256) void k_lin(const float* f, const float* fsa, const unsigned short* wbl, const float* bl,
                                             unsigned short* ybuf, float* part){
  __shared__ float psum[4][128], psq[4][128];
  int tid=threadIdx.x, wave=tid>>6, lane=tid&63, lr=lane&15, lg=lane>>4;
  long r0 = (long)blockIdx.x*64 + wave*16;
  bf16x8 a[4];
  {
    const float* fr = f + (r0+lr)*ND;
    const float* sr = fsa + (r0+lr)*ND;
    #pragma unroll
    for (int ks=0;ks<4;ks++){
      bf16x8 t;
      #pragma unroll
      for (int j=0;j<8;j++){
        int d = ks*32 + lg*8 + j;
        t[j] = (short)f2bf(fr[d] - sr[d]);
      }
      a[ks] = t;
    }
  }
  #pragma unroll
  for (int cs=0;cs<8;cs++){
    f32x4 acc = {0.f,0.f,0.f,0.f};
    #pragma unroll
    for (int ks=0;ks<4;ks++){
      bf16x8 bfr = *(const bf16x8*)(wbl + (cs*16+lr)*ND + ks*32 + lg*8);
      acc = __builtin_amdgcn_mfma_f32_16x16x32_bf16(a[ks], bfr, acc, 0, 0, 0);
    }
    float bias = bl[cs*16+lr];
    float l1=0.f, l2=0.f;
    #pragma unroll
    for (int r=0;r<4;r++){
      float y = acc[r] + bias;
      ybuf[(r0 + lg*4 + r)*ND + cs*16 + lr] = f2bf(y);
      l1 += y; l2 += y*y;
    }
    l1 += __shfl_xor(l1,16,64); l1 += __shfl_xor(l1,32,64);
    l2 += __shfl_xor(l2,16,64); l2 += __shfl_xor(l2,32,64);
    if (lg==0){ psum[wave][cs*16+lr] = l1; psq[wave][cs*16+lr] = l2; }
  }
  __syncthreads();
  if (tid < 128){
    float t1 = psum[0][tid]+psum[1][tid]+psum[2][tid]+psum[3][tid];
    float t2 = psq[0][tid]+psq[1][tid]+psq[2][tid]+psq[3][tid];
    part[tid*512 + blockIdx.x] = t1;
    part[65536 + tid*512 + blockIdx.x] = t2;
  }
}

// ---------------- k_bnred: deterministic per-channel reduction of 512 block partials ----------------
__global__ __launch_bounds__(64) void k_bnred(const float* part, float* bnstat){
  int c = blockIdx.x, t = threadIdx.x;
  float s=0.f, q=0.f;
  for (int i=t; i<512; i+=64){ s += part[c*512+i]; q += part[65536 + c*512+i]; }
  #pragma unroll
  for (int m=1; m<64; m<<=1){ s += __shfl_xor(s,m,64); q += __shfl_xor(q,m,64); }
  if (t==0){ bnstat[c] = s; bnstat[128+c] = q; }
}

// ---------------- k_final: out = relu(bn(y)) + fsa ----------------
__global__ __launch_bounds__(256) void k_final(const unsigned short* ybuf, const float* fsa, const float* bnstat,
                                               const float* gamma, const float* beta, float* out){
  long i0 = ((long)blockIdx.x*256 + threadIdx.x)*8;
  int c0 = (int)(i0 & (ND-1));
  bf16x8 yv = *(const bf16x8*)(ybuf + i0);
  f32x4 f0 = *(const f32x4*)(fsa + i0);
  f32x4 f1 = *(const f32x4*)(fsa + i0 + 4);
  f32x4 o0, o1;
  #pragma unroll
  for (int j=0;j<8;j++){
    int c = c0 + j;
    float mean = bnstat[c] * (1.f/(float)NS);
    float var  = bnstat[128+c] * (1.f/(float)NS) - mean*mean;
    float rstd = rsqrtf(var + 1e-5f);
    float y = bf2f((unsigned short)yv[j]);
    float v = gamma[c]*(y-mean)*rstd + beta[c];
    v = v > 0.f ? v : 0.f;
    float add = (j<4) ? f0[j] : f1[j-4];
    if (j<4) o0[j] = v + add; else o1[j-4] = v + add;
  }
  *(f32x4*)(out + i0) = o0;
  *(f32x4*)(out + i0 + 4) = o1;
}

extern "C" void kernel_launch(void* const* d_in, const int* in_sizes, int n_in,
                              void* d_out, int out_size, void* d_ws, size_t ws_size,
                              hipStream_t stream){
  const float* f_in  = (const float*)d_in[0];
  const float* w_q   = (const float*)d_in[1];
  const float* b_q   = (const float*)d_in[2];
  const float* w_k   = (const float*)d_in[3];
  const float* b_k   = (const float*)d_in[4];
  const float* w_v   = (const float*)d_in[5];
  const float* b_v   = (const float*)d_in[6];
  const float* w_l   = (const float*)d_in[7];
  const float* b_l   = (const float*)d_in[8];
  const float* gamma = (const float*)d_in[9];
  const float* beta  = (const float*)d_in[10];
  float* out = (float*)d_out;
  char* ws = (char*)d_ws;

  unsigned short* wbq = (unsigned short*)(ws + 0);
  unsigned short* wbk = (unsigned short*)(ws + 8192);
  unsigned short* wbv = (unsigned short*)(ws + 16384);
  unsigned short* wbl = (unsigned short*)(ws + 49152);
  unsigned short* Qb  = (unsigned short*)(ws + 81920);
  unsigned short* Kb  = (unsigned short*)(ws + 2179072);
  unsigned short* Vb  = (unsigned short*)(ws + 4276224);
  float*          wrcp= (float*)(ws + 12664832);
  unsigned short* VT  = (unsigned short*)(ws + 12795904);
  float*          fsa = (float*)(ws + 22233088);
  unsigned short* ybuf= (unsigned short*)(ws + 39010304);
  float*          part= (float*)(ws + 47398912);
  float*          bnst= (float*)(ws + 47923200);

  k_prep  <<<160, 256, 0, stream>>>(w_q, w_k, w_v, w_l, wbq, wbk, wbv, wbl);
  k_qkv   <<<512, 256, 0, stream>>>(f_in, wbq, wbk, wbv, b_q, b_k, b_v, Qb, Kb, Vb);
  k_colsum<<<512, 256, 0, stream>>>(Qb, Kb, wrcp);
  k_vprime<<<512, 256, 0, stream>>>(Vb, wrcp, VT);
  k_pv    <<<512, 256, 0, stream>>>(Qb, Kb, VT, fsa);
  k_lin   <<<512, 256, 0, stream>>>(f_in, fsa, wbl, b_l, ybuf, part);
  k_bnred <<<128, 64, 0, stream>>>(part, bnst);
  k_final <<<2048,256, 0, stream>>>(ybuf, fsa, bnst, gamma, beta, out);
}

// Round 2
// 136.433 us; speedup vs baseline: 1.2733x; 1.2733x over previous
//
#include <hip/hip_runtime.h>
#include <stdint.h>

#define NB 16
#define NN 2048
#define ND 128
#define NH 32
#define NS (NB*NN)

typedef __attribute__((ext_vector_type(8))) short bf16x8;
typedef __attribute__((ext_vector_type(4))) float f32x4;

__device__ __forceinline__ unsigned short f2bf(float f){
  union { float f; unsigned int u; } v; v.f = f;
  unsigned int r = v.u + 0x7fffu + ((v.u >> 16) & 1u);
  return (unsigned short)(r >> 16);
}
__device__ __forceinline__ float bf2f(unsigned short u){
  union { unsigned int u; float f; } v; v.u = ((unsigned int)u) << 16;
  return v.f;
}
// raw 2^x (Q is pre-scaled by log2e, so exp(S) == exp2(S'))
__device__ __forceinline__ float fexp2(float x){
  float r; asm("v_exp_f32 %0, %1" : "=v"(r) : "v"(x)); return r;
}

// ---------------- k_prep: fp32 weights -> bf16 ----------------
__global__ __launch_bounds__(256) void k_prep(const float* wq, const float* wk, const float* wv, const float* wl,
                                              unsigned short* oq, unsigned short* ok, unsigned short* ov, unsigned short* ol){
  int i = blockIdx.x*256 + threadIdx.x;
  if (i < 4096) oq[i] = f2bf(wq[i]);
  else if (i < 8192) ok[i-4096] = f2bf(wk[i-4096]);
  else if (i < 24576) ov[i-8192] = f2bf(wv[i-8192]);
  else if (i < 40960) ol[i-24576] = f2bf(wl[i-24576]);
}

// ---------------- k_qkv: Q (scaled by log2e), K (S x 32), V (S x 128) in bf16 ----------------
__global__ __launch_bounds__(256) void k_qkv(const float* f, const unsigned short* wbq, const unsigned short* wbk,
                                             const unsigned short* wbv, const float* bq, const float* bk, const float* bv,
                                             unsigned short* Qb, unsigned short* Kb, unsigned short* Vb){
  int tid = threadIdx.x, wave = tid>>6, lane = tid&63, lr = lane&15, lg = lane>>4;
  long r0 = (long)blockIdx.x*64 + wave*16;
  bf16x8 a[4];
  const float* frow = f + (r0 + lr)*ND;
  #pragma unroll
  for (int ks=0; ks<4; ks++){
    const float* p = frow + ks*32 + lg*8;
    bf16x8 t;
    #pragma unroll
    for (int j=0;j<8;j++) t[j] = (short)f2bf(p[j]);
    a[ks] = t;
  }
  #pragma unroll
  for (int cs=0; cs<12; cs++){
    const unsigned short* wsrc; const float* bsrc; int cl;
    if (cs<2){ wsrc=wbq; bsrc=bq; cl=cs*16; }
    else if (cs<4){ wsrc=wbk; bsrc=bk; cl=(cs-2)*16; }
    else { wsrc=wbv; bsrc=bv; cl=(cs-4)*16; }
    f32x4 acc = {0.f,0.f,0.f,0.f};
    #pragma unroll
    for (int ks=0;ks<4;ks++){
      bf16x8 b = *(const bf16x8*)(wsrc + (cl+lr)*ND + ks*32 + lg*8);
      acc = __builtin_amdgcn_mfma_f32_16x16x32_bf16(a[ks], b, acc, 0, 0, 0);
    }
    float bias = bsrc[cl + lr];
    #pragma unroll
    for (int r=0;r<4;r++){
      float v = acc[r] + bias;
      if (cs<2) v *= 1.4426950408889634f;   // fold log2(e) into Q
      long row = r0 + lg*4 + r;
      if (cs<2) Qb[row*NH + cl+lr] = f2bf(v);
      else if (cs<4) Kb[row*NH + cl+lr] = f2bf(v);
      else Vb[row*ND + cl+lr] = f2bf(v);
    }
  }
}

// ---------------- k_csv: colsum (wrcp in LDS) + V' transpose/scale, fused ----------------
__global__ __launch_bounds__(256) void k_csv(const unsigned short* Qb, const unsigned short* Kb,
                                             const unsigned short* Vb, unsigned short* VT){
  __shared__ unsigned short tr[128][65];
  __shared__ float wsh[64];
  int tid=threadIdx.x, wave=tid>>6, lane=tid&63, lr=lane&15, lg=lane>>4;
  int wg = (blockIdx.x & 7)*64 + (blockIdx.x >> 3);   // XCD-chunked swizzle (512 % 8 == 0)
  int b = wg >> 5;
  int m0 = (wg & 31)*64;
  const unsigned short* Qbb = Qb + (long)b*NN*NH;
  const unsigned short* Kbb = Kb + (long)b*NN*NH;
  const unsigned short* Vbb = Vb + ((long)b*NN + m0)*ND;
  bf16x8 vreg[4];
  #pragma unroll
  for (int it=0; it<4; it++){
    int i = it*256 + tid;
    int r = i >> 4, c8 = (i & 15)*8;
    vreg[it] = *(const bf16x8*)(Vbb + r*ND + c8);
  }
  bf16x8 kf = *(const bf16x8*)(Kbb + (m0 + wave*16 + lr)*NH + lg*8);
  float csum = 0.f;
  for (int n0=0; n0<NN; n0+=64){
    #pragma unroll
    for (int u=0; u<4; u++){
      bf16x8 qf = *(const bf16x8*)(Qbb + (n0+u*16+lr)*NH + lg*8);
      f32x4 c = {0.f,0.f,0.f,0.f};
      c = __builtin_amdgcn_mfma_f32_16x16x32_bf16(qf, kf, c, 0, 0, 0);
      csum += fexp2(c[0]) + fexp2(c[1]) + fexp2(c[2]) + fexp2(c[3]);
    }
  }
  csum += __shfl_xor(csum, 16, 64);
  csum += __shfl_xor(csum, 32, 64);
  #pragma unroll
  for (int it=0; it<4; it++){
    int i = it*256 + tid;
    int r = i >> 4, c8 = (i & 15)*8;
    #pragma unroll
    for (int j=0;j<8;j++) tr[c8+j][r] = (unsigned short)vreg[it][j];
  }
  if (lg == 0) wsh[wave*16 + lr] = 1.f / csum;
  __syncthreads();
  unsigned short* VTb = VT + (long)b*144*NN;
  #pragma unroll
  for (int it=0; it<9; it++){
    int i = it*256 + tid;
    int e = i >> 4, m4 = (i & 15)*4;
    ushort4 o;
    if (e < 128){
      o.x = f2bf(bf2f(tr[e][m4+0]) * wsh[m4+0]);
      o.y = f2bf(bf2f(tr[e][m4+1]) * wsh[m4+1]);
      o.z = f2bf(bf2f(tr[e][m4+2]) * wsh[m4+2]);
      o.w = f2bf(bf2f(tr[e][m4+3]) * wsh[m4+3]);
    } else if (e == 128){
      o.x = f2bf(wsh[m4+0]); o.y = f2bf(wsh[m4+1]);
      o.z = f2bf(wsh[m4+2]); o.w = f2bf(wsh[m4+3]);
    } else { o.x = o.y = o.z = o.w = 0; }
    *(ushort4*)(VTb + (long)e*NN + m0 + m4) = o;
  }
}

// ---------------- k_pv: f_sa = (E @ V') / (E @ w), double-buffered global_load_lds staging ----------------
__global__ __launch_bounds__(256) void k_pv(const unsigned short* Qb, const unsigned short* Kb,
                                            const unsigned short* VT, float* fsa){
  __shared__ __align__(16) unsigned char vts[2][144*128];
  __shared__ __align__(16) unsigned char es[4][16*128];
  __shared__ float rdl[4][16];
  int tid=threadIdx.x, wave=tid>>6, lane=tid&63, lr=lane&15, lg=lane>>4;
  int wg = (blockIdx.x & 7)*64 + (blockIdx.x >> 3);   // XCD-chunked swizzle
  int b = wg >> 5;
  int nloc = (wg & 31)*64 + wave*16;
  const unsigned short* Qbb = Qb + (long)b*NN*NH;
  const unsigned short* Kbb = Kb + (long)b*NN*NH;
  const unsigned short* VTb = VT + (long)b*144*NN;

  auto stage = [&](int buf, int m0c){
    for (int i = wave; i < 18; i += 4){
      int v = i*64 + lane;
      int e = v >> 3, blk = v & 7;
      int mb = (blk*16) ^ ((e&7)<<4);   // pre-swizzled source column (bytes)
      __builtin_amdgcn_global_load_lds(
        (const __attribute__((address_space(1))) unsigned int*)(VTb + (long)e*NN + m0c + (mb>>1)),
        (__attribute__((address_space(3))) unsigned int*)(vts[buf] + i*1024), 16, 0, 0);
    }
  };

  bf16x8 qf = *(const bf16x8*)(Qbb + (nloc+lr)*NH + lg*8);
  f32x4 acc[9];
  #pragma unroll
  for (int cs=0;cs<9;cs++) acc[cs] = (f32x4){0.f,0.f,0.f,0.f};

  stage(0, 0);
  __syncthreads();
  int cur = 0;
  for (int m0 = 0; m0 < NN; m0 += 64){
    if (m0 + 64 < NN) stage(cur^1, m0 + 64);
    #pragma unroll
    for (int s=0; s<4; s++){
      bf16x8 kf = *(const bf16x8*)(Kbb + (m0 + s*16 + lr)*NH + lg*8);
      f32x4 c = {0.f,0.f,0.f,0.f};
      c = __builtin_amdgcn_mfma_f32_16x16x32_bf16(qf, kf, c, 0, 0, 0);
      #pragma unroll
      for (int r=0;r<4;r++){
        int row = lg*4 + r;
        int col = s*16 + lr;
        unsigned short ev = f2bf(fexp2(c[r]));
        *(unsigned short*)(es[wave] + row*128 + ((col*2) ^ ((row&7)<<4))) = ev;
      }
    }
    __builtin_amdgcn_s_setprio(1);
    #pragma unroll
    for (int ks=0; ks<2; ks++){
      bf16x8 ea = *(const bf16x8*)(es[wave] + lr*128 + (((ks*32 + lg*8)*2) ^ ((lr&7)<<4)));
      #pragma unroll
      for (int cs=0; cs<9; cs++){
        int e = cs*16 + lr;
        bf16x8 vb = *(const bf16x8*)(vts[cur] + e*128 + (((ks*32 + lg*8)*2) ^ ((e&7)<<4)));
        acc[cs] = __builtin_amdgcn_mfma_f32_16x16x32_bf16(ea, vb, acc[cs], 0, 0, 0);
      }
    }
    __builtin_amdgcn_s_setprio(0);
    __syncthreads();
    cur ^= 1;
  }
  if (lr == 0){
    #pragma unroll
    for (int r=0;r<4;r++) rdl[wave][lg*4+r] = acc[8][r];
  }
  __syncthreads();
  long grow0 = (long)b*NN + nloc;
  #pragma unroll
  for (int r=0;r<4;r++){
    int row = lg*4 + r;
    float rinv = 1.f / rdl[wave][row];
    #pragma unroll
    for (int cs=0;cs<8;cs++){
      fsa[(grow0 + row)*ND + cs*16 + lr] = acc[cs][r] * rinv;
    }
  }
}

// ---------------- k_lin ----------------
__global__ __launch_bounds__(256) void k_lin(const float* f, const float* fsa, const unsigned short* wbl, const float* bl,
                                             unsigned short* ybuf, float* part){
  __shared__ float psum[4][128], psq[4][128];
  int tid=threadIdx.x, wave=tid>>6, lane=tid&63, lr=lane&15, lg=lane>>4;
  long r0 = (long)blockIdx.x*64 + wave*16;
  bf16x8 a[4];
  {
    const float* fr = f + (r0+lr)*ND;
    const float* sr = fsa + (r0+lr)*ND;
    #pragma unroll
    for (int ks=0;ks<4;ks++){
      bf16x8 t;
      #pragma unroll
      for (int j=0;j<8;j++){
        int d = ks*32 + lg*8 + j;
        t[j] = (short)f2bf(fr[d] - sr[d]);
      }
      a[ks] = t;
    }
  }
  #pragma unroll
  for (int cs=0;cs<8;cs++){
    f32x4 acc = {0.f,0.f,0.f,0.f};
    #pragma unroll
    for (int ks=0;ks<4;ks++){
      bf16x8 bfr = *(const bf16x8*)(wbl + (cs*16+lr)*ND + ks*32 + lg*8);
      acc = __builtin_amdgcn_mfma_f32_16x16x32_bf16(a[ks], bfr, acc, 0, 0, 0);
    }
    float bias = bl[cs*16+lr];
    float l1=0.f, l2=0.f;
    #pragma unroll
    for (int r=0;r<4;r++){
      float y = acc[r] + bias;
      ybuf[(r0 + lg*4 + r)*ND + cs*16 + lr] = f2bf(y);
      l1 += y; l2 += y*y;
    }
    l1 += __shfl_xor(l1,16,64); l1 += __shfl_xor(l1,32,64);
    l2 += __shfl_xor(l2,16,64); l2 += __shfl_xor(l2,32,64);
    if (lg==0){ psum[wave][cs*16+lr] = l1; psq[wave][cs*16+lr] = l2; }
  }
  __syncthreads();
  if (tid < 128){
    float t1 = psum[0][tid]+psum[1][tid]+psum[2][tid]+psum[3][tid];
    float t2 = psq[0][tid]+psq[1][tid]+psq[2][tid]+psq[3][tid];
    part[tid*512 + blockIdx.x] = t1;
    part[65536 + tid*512 + blockIdx.x] = t2;
  }
}

// ---------------- k_bnred: per-channel reduction -> BN scale/shift ----------------
__global__ __launch_bounds__(64) void k_bnred(const float* part, const float* gamma, const float* beta, float* bnstat){
  int c = blockIdx.x, t = threadIdx.x;
  float s=0.f, q=0.f;
  for (int i=t; i<512; i+=64){ s += part[c*512+i]; q += part[65536 + c*512+i]; }
  #pragma unroll
  for (int m=1; m<64; m<<=1){ s += __shfl_xor(s,m,64); q += __shfl_xor(q,m,64); }
  if (t==0){
    float mean = s * (1.f/(float)NS);
    float var  = q * (1.f/(float)NS) - mean*mean;
    float rstd = rsqrtf(var + 1e-5f);
    float sc = gamma[c]*rstd;
    bnstat[c] = sc;
    bnstat[128+c] = beta[c] - mean*sc;
  }
}

// ---------------- k_final: out = relu(y*scale + shift) + fsa ----------------
__global__ __launch_bounds__(256) void k_final(const unsigned short* ybuf, const float* fsa, const float* bnstat,
                                               float* out){
  long i0 = ((long)blockIdx.x*256 + threadIdx.x)*8;
  int c0 = (int)(i0 & (ND-1));
  bf16x8 yv = *(const bf16x8*)(ybuf + i0);
  f32x4 f0 = *(const f32x4*)(fsa + i0);
  f32x4 f1 = *(const f32x4*)(fsa + i0 + 4);
  f32x4 o0, o1;
  #pragma unroll
  for (int j=0;j<8;j++){
    int c = c0 + j;
    float v = bf2f((unsigned short)yv[j]) * bnstat[c] + bnstat[128+c];
    v = v > 0.f ? v : 0.f;
    float add = (j<4) ? f0[j] : f1[j-4];
    if (j<4) o0[j] = v + add; else o1[j-4] = v + add;
  }
  *(f32x4*)(out + i0) = o0;
  *(f32x4*)(out + i0 + 4) = o1;
}

extern "C" void kernel_launch(void* const* d_in, const int* in_sizes, int n_in,
                              void* d_out, int out_size, void* d_ws, size_t ws_size,
                              hipStream_t stream){
  const float* f_in  = (const float*)d_in[0];
  const float* w_q   = (const float*)d_in[1];
  const float* b_q   = (const float*)d_in[2];
  const float* w_k   = (const float*)d_in[3];
  const float* b_k   = (const float*)d_in[4];
  const float* w_v   = (const float*)d_in[5];
  const float* b_v   = (const float*)d_in[6];
  const float* w_l   = (const float*)d_in[7];
  const float* b_l   = (const float*)d_in[8];
  const float* gamma = (const float*)d_in[9];
  const float* beta  = (const float*)d_in[10];
  float* out = (float*)d_out;
  char* ws = (char*)d_ws;

  unsigned short* wbq = (unsigned short*)(ws + 0);
  unsigned short* wbk = (unsigned short*)(ws + 8192);
  unsigned short* wbv = (unsigned short*)(ws + 16384);
  unsigned short* wbl = (unsigned short*)(ws + 49152);
  unsigned short* Qb  = (unsigned short*)(ws + 81920);
  unsigned short* Kb  = (unsigned short*)(ws + 2179072);
  unsigned short* Vb  = (unsigned short*)(ws + 4276224);
  unsigned short* VT  = (unsigned short*)(ws + 12795904);
  float*          fsa = (float*)(ws + 22233088);
  unsigned short* ybuf= (unsigned short*)(ws + 39010304);
  float*          part= (float*)(ws + 47398912);
  float*          bnst= (float*)(ws + 47923200);

  k_prep  <<<160, 256, 0, stream>>>(w_q, w_k, w_v, w_l, wbq, wbk, wbv, wbl);
  k_qkv   <<<512, 256, 0, stream>>>(f_in, wbq, wbk, wbv, b_q, b_k, b_v, Qb, Kb, Vb);
  k_csv   <<<512, 256, 0, stream>>>(Qb, Kb, Vb, VT);
  k_pv    <<<512, 256, 0, stream>>>(Qb, Kb, VT, fsa);
  k_lin   <<<512, 256, 0, stream>>>(f_in, fsa, wbl, b_l, ybuf, part);
  k_bnred <<<128, 64, 0, stream>>>(part, gamma, beta, bnst);
  k_final <<<2048,256, 0, stream>>>(ybuf, fsa, bnst, out);
}

// Round 3
// 125.876 us; speedup vs baseline: 1.3801x; 1.0839x over previous
//
#include <hip/hip_runtime.h>
#include <stdint.h>

#define NB 16
#define NN 2048
#define ND 128
#define NH 32
#define NS (NB*NN)
#define NT 32   // m-chunks of 64 in k_pv

typedef __attribute__((ext_vector_type(8))) short bf16x8;
typedef __attribute__((ext_vector_type(4))) float f32x4;

__device__ __forceinline__ unsigned short f2bf(float f){
  union { float f; unsigned int u; } v; v.f = f;
  unsigned int r = v.u + 0x7fffu + ((v.u >> 16) & 1u);
  return (unsigned short)(r >> 16);
}
__device__ __forceinline__ float bf2f(unsigned short u){
  union { unsigned int u; float f; } v; v.u = ((unsigned int)u) << 16;
  return v.f;
}
// raw 2^x (Q is pre-scaled by log2e, so exp(S) == exp2(S'))
__device__ __forceinline__ float fexp2(float x){
  float r; asm("v_exp_f32 %0, %1" : "=v"(r) : "v"(x)); return r;
}

// ---------------- k_prep: fp32 weights -> bf16 ----------------
__global__ __launch_bounds__(256) void k_prep(const float* wq, const float* wk, const float* wv, const float* wl,
                                              unsigned short* oq, unsigned short* ok, unsigned short* ov, unsigned short* ol){
  int i = blockIdx.x*256 + threadIdx.x;
  if (i < 4096) oq[i] = f2bf(wq[i]);
  else if (i < 8192) ok[i-4096] = f2bf(wk[i-4096]);
  else if (i < 24576) ov[i-8192] = f2bf(wv[i-8192]);
  else if (i < 40960) ol[i-24576] = f2bf(wl[i-24576]);
}

// ---------------- k_qkv: Q (scaled by log2e), K (S x 32), V (S x 128) in bf16 ----------------
__global__ __launch_bounds__(256) void k_qkv(const float* f, const unsigned short* wbq, const unsigned short* wbk,
                                             const unsigned short* wbv, const float* bq, const float* bk, const float* bv,
                                             unsigned short* Qb, unsigned short* Kb, unsigned short* Vb){
  int tid = threadIdx.x, wave = tid>>6, lane = tid&63, lr = lane&15, lg = lane>>4;
  long r0 = (long)blockIdx.x*64 + wave*16;
  bf16x8 a[4];
  const float* frow = f + (r0 + lr)*ND;
  #pragma unroll
  for (int ks=0; ks<4; ks++){
    const float* p = frow + ks*32 + lg*8;
    bf16x8 t;
    #pragma unroll
    for (int j=0;j<8;j++) t[j] = (short)f2bf(p[j]);
    a[ks] = t;
  }
  #pragma unroll
  for (int cs=0; cs<12; cs++){
    const unsigned short* wsrc; const float* bsrc; int cl;
    if (cs<2){ wsrc=wbq; bsrc=bq; cl=cs*16; }
    else if (cs<4){ wsrc=wbk; bsrc=bk; cl=(cs-2)*16; }
    else { wsrc=wbv; bsrc=bv; cl=(cs-4)*16; }
    f32x4 acc = {0.f,0.f,0.f,0.f};
    #pragma unroll
    for (int ks=0;ks<4;ks++){
      bf16x8 b = *(const bf16x8*)(wsrc + (cl+lr)*ND + ks*32 + lg*8);
      acc = __builtin_amdgcn_mfma_f32_16x16x32_bf16(a[ks], b, acc, 0, 0, 0);
    }
    float bias = bsrc[cl + lr];
    #pragma unroll
    for (int r=0;r<4;r++){
      float v = acc[r] + bias;
      if (cs<2) v *= 1.4426950408889634f;   // fold log2(e) into Q
      long row = r0 + lg*4 + r;
      if (cs<2) Qb[row*NH + cl+lr] = f2bf(v);
      else if (cs<4) Kb[row*NH + cl+lr] = f2bf(v);
      else Vb[row*ND + cl+lr] = f2bf(v);
    }
  }
}

// ---------------- k_csv: colsum (wrcp in LDS) + V' transpose/scale, fused ----------------
__global__ __launch_bounds__(256) void k_csv(const unsigned short* Qb, const unsigned short* Kb,
                                             const unsigned short* Vb, unsigned short* VT){
  __shared__ unsigned short tr[128][65];
  __shared__ float wsh[64];
  int tid=threadIdx.x, wave=tid>>6, lane=tid&63, lr=lane&15, lg=lane>>4;
  int wg = (blockIdx.x & 7)*64 + (blockIdx.x >> 3);   // XCD-chunked swizzle (512 % 8 == 0)
  int b = wg >> 5;
  int m0 = (wg & 31)*64;
  const unsigned short* Qbb = Qb + (long)b*NN*NH;
  const unsigned short* Kbb = Kb + (long)b*NN*NH;
  const unsigned short* Vbb = Vb + ((long)b*NN + m0)*ND;
  bf16x8 vreg[4];
  #pragma unroll
  for (int it=0; it<4; it++){
    int i = it*256 + tid;
    int r = i >> 4, c8 = (i & 15)*8;
    vreg[it] = *(const bf16x8*)(Vbb + r*ND + c8);
  }
  bf16x8 kf = *(const bf16x8*)(Kbb + (m0 + wave*16 + lr)*NH + lg*8);
  float csum = 0.f;
  for (int n0=0; n0<NN; n0+=64){
    #pragma unroll
    for (int u=0; u<4; u++){
      bf16x8 qf = *(const bf16x8*)(Qbb + (n0+u*16+lr)*NH + lg*8);
      f32x4 c = {0.f,0.f,0.f,0.f};
      c = __builtin_amdgcn_mfma_f32_16x16x32_bf16(qf, kf, c, 0, 0, 0);
      csum += fexp2(c[0]) + fexp2(c[1]) + fexp2(c[2]) + fexp2(c[3]);
    }
  }
  csum += __shfl_xor(csum, 16, 64);
  csum += __shfl_xor(csum, 32, 64);
  #pragma unroll
  for (int it=0; it<4; it++){
    int i = it*256 + tid;
    int r = i >> 4, c8 = (i & 15)*8;
    #pragma unroll
    for (int j=0;j<8;j++) tr[c8+j][r] = (unsigned short)vreg[it][j];
  }
  if (lg == 0) wsh[wave*16 + lr] = 1.f / csum;
  __syncthreads();
  unsigned short* VTb = VT + (long)b*144*NN;
  #pragma unroll
  for (int it=0; it<9; it++){
    int i = it*256 + tid;
    int e = i >> 4, m4 = (i & 15)*4;
    ushort4 o;
    if (e < 128){
      o.x = f2bf(bf2f(tr[e][m4+0]) * wsh[m4+0]);
      o.y = f2bf(bf2f(tr[e][m4+1]) * wsh[m4+1]);
      o.z = f2bf(bf2f(tr[e][m4+2]) * wsh[m4+2]);
      o.w = f2bf(bf2f(tr[e][m4+3]) * wsh[m4+3]);
    } else if (e == 128){
      o.x = f2bf(wsh[m4+0]); o.y = f2bf(wsh[m4+1]);
      o.z = f2bf(wsh[m4+2]); o.w = f2bf(wsh[m4+3]);
    } else { o.x = o.y = o.z = o.w = 0; }
    *(ushort4*)(VTb + (long)e*NN + m0 + m4) = o;
  }
}

// ---------------- k_pv: f_sa = (E @ V') / (E @ w) ----------------
// Counted-vmcnt pipeline: VT triple-buffered, K double-buffered, all staging via
// global_load_lds (uniform 6 loads/wave/chunk: 5 VT + 1 K). Raw s_barrier + vmcnt(5).
__global__ __launch_bounds__(256) void k_pv(const unsigned short* Qb, const unsigned short* Kb,
                                            const unsigned short* VT, float* fsa){
  __shared__ __align__(16) unsigned char vbuf[3][20480];  // 160 rows x 128B (rows>=144 staged, never read)
  __shared__ __align__(16) unsigned char kbuf[2][4096];   // 64 rows x 64B, swizzled
  __shared__ __align__(16) unsigned char es[4][2048];     // per-wave E tile, swizzled
  int tid=threadIdx.x, wave=tid>>6, lane=tid&63, lr=lane&15, lg=lane>>4;
  int wg = (blockIdx.x & 7)*64 + (blockIdx.x >> 3);       // XCD-chunked swizzle
  int b = wg >> 5;
  int nloc = (wg & 31)*64 + wave*16;
  const unsigned short* Qbb = Qb + (long)b*NN*NH;
  const unsigned short* Kbb = Kb + (long)b*NN*NH;
  const unsigned short* VTb = VT + (long)b*144*NN;

  int vrow_lo = lane>>3;   // row within 8-row group (VT)
  int vblk    = lane&7;    // 16B block within 128B row (VT)
  int krow_lo = lane>>2;   // row within 16-row group (K)
  int kblk    = lane&3;    // 16B block within 64B row (K)

  auto stageV = [&](int buf, int m0c){
    #pragma unroll
    for (int t=0;t<5;t++){
      int i = wave*5 + t;                 // instr 0..19 -> rows 8i..8i+7
      int e = i*8 + vrow_lo;
      int sblk = vblk ^ (e&7);            // pre-swizzled source block
      __builtin_amdgcn_global_load_lds(
        (const __attribute__((address_space(1))) unsigned int*)(VTb + (long)e*NN + m0c + sblk*8),
        (__attribute__((address_space(3))) unsigned int*)(&vbuf[buf][i*1024]), 16, 0, 0);
    }
  };
  auto stageK = [&](int buf, int m0c){
    int r = wave*16 + krow_lo;
    int sblk = kblk ^ ((krow_lo>>1)&3);   // pre-swizzled source block
    __builtin_amdgcn_global_load_lds(
      (const __attribute__((address_space(1))) unsigned int*)(Kbb + (long)(m0c + r)*NH + sblk*8),
      (__attribute__((address_space(3))) unsigned int*)(&kbuf[buf][wave*1024]), 16, 0, 0);
  };

  bf16x8 qf = *(const bf16x8*)(Qbb + (nloc+lr)*NH + lg*8);
  f32x4 acc[9];
  #pragma unroll
  for (int cs=0;cs<9;cs++) acc[cs] = (f32x4){0.f,0.f,0.f,0.f};

  // prologue issue order: VT(0)x5, K(0), VT(1)x5  -> uniform vmcnt(5) works from iter 0
  stageV(0, 0);
  stageK(0, 0);
  stageV(1, 64);

  int vc = 0, kc = 0, vn2 = 2;
  for (int it = 0; it < NT; ++it){
    int m0 = it<<6;
    if (it < NT-1) asm volatile("s_waitcnt vmcnt(5)" ::: "memory");
    else           asm volatile("s_waitcnt vmcnt(0)" ::: "memory");
    __builtin_amdgcn_s_barrier();
    if (it+1 < NT) stageK(kc^1, m0+64);     // lands by iter it+1
    if (it+2 < NT) stageV(vn2, m0+128);     // lands by iter it+2
    // ---- score phase: E = exp2(Q'K^T) -> per-wave LDS tile ----
    #pragma unroll
    for (int s=0;s<4;s++){
      bf16x8 kf = *(const bf16x8*)(&kbuf[kc][(s*16+lr)*64 + ((lg ^ ((lr>>1)&3))<<4)]);
      f32x4 c = {0.f,0.f,0.f,0.f};
      c = __builtin_amdgcn_mfma_f32_16x16x32_bf16(qf, kf, c, 0, 0, 0);
      #pragma unroll
      for (int r=0;r<4;r++){
        int row = lg*4 + r, col = s*16 + lr;
        *(unsigned short*)(&es[wave][(row<<7) + ((col*2) ^ ((row&7)<<4))]) = f2bf(fexp2(c[r]));
      }
    }
    // ---- PV phase: acc[cs] += E(16x64) @ V'(64x144) ----
    __builtin_amdgcn_s_setprio(1);
    #pragma unroll
    for (int ks=0; ks<2; ks++){
      bf16x8 ea = *(const bf16x8*)(&es[wave][(lr<<7) + ((ks*64 + (lg<<4)) ^ ((lr&7)<<4))]);
      #pragma unroll
      for (int cs=0; cs<9; cs++){
        int e = cs*16 + lr;
        bf16x8 vb = *(const bf16x8*)(&vbuf[vc][(e<<7) + ((ks*64 + (lg<<4)) ^ ((e&7)<<4))]);
        acc[cs] = __builtin_amdgcn_mfma_f32_16x16x32_bf16(ea, vb, acc[cs], 0, 0, 0);
      }
    }
    __builtin_amdgcn_s_setprio(0);
    vc = (vc==2)?0:vc+1;
    vn2 = (vn2==2)?0:vn2+1;
    kc ^= 1;
  }
  // denominator: acc[8][r] at lanes lr==0 (V' col 128); broadcast within 16-lane group
  long grow0 = (long)b*NN + nloc;
  #pragma unroll
  for (int r=0;r<4;r++){
    float den = __shfl(acc[8][r], lane & 48, 64);
    float rinv = 1.f / den;
    int row = lg*4 + r;
    #pragma unroll
    for (int cs=0;cs<8;cs++)
      fsa[(grow0 + row)*ND + cs*16 + lr] = acc[cs][r] * rinv;
  }
}

// ---------------- k_lin ----------------
__global__ __launch_bounds__(256) void k_lin(const float* f, const float* fsa, const unsigned short* wbl, const float* bl,
                                             unsigned short* ybuf, float* part){
  __shared__ float psum[4][128], psq[4][128];
  int tid=threadIdx.x, wave=tid>>6, lane=tid&63, lr=lane&15, lg=lane>>4;
  long r0 = (long)blockIdx.x*64 + wave*16;
  bf16x8 a[4];
  {
    const float* fr = f + (r0+lr)*ND;
    const float* sr = fsa + (r0+lr)*ND;
    #pragma unroll
    for (int ks=0;ks<4;ks++){
      bf16x8 t;
      #pragma unroll
      for (int j=0;j<8;j++){
        int d = ks*32 + lg*8 + j;
        t[j] = (short)f2bf(fr[d] - sr[d]);
      }
      a[ks] = t;
    }
  }
  #pragma unroll
  for (int cs=0;cs<8;cs++){
    f32x4 acc = {0.f,0.f,0.f,0.f};
    #pragma unroll
    for (int ks=0;ks<4;ks++){
      bf16x8 bfr = *(const bf16x8*)(wbl + (cs*16+lr)*ND + ks*32 + lg*8);
      acc = __builtin_amdgcn_mfma_f32_16x16x32_bf16(a[ks], bfr, acc, 0, 0, 0);
    }
    float bias = bl[cs*16+lr];
    float l1=0.f, l2=0.f;
    #pragma unroll
    for (int r=0;r<4;r++){
      float y = acc[r] + bias;
      ybuf[(r0 + lg*4 + r)*ND + cs*16 + lr] = f2bf(y);
      l1 += y; l2 += y*y;
    }
    l1 += __shfl_xor(l1,16,64); l1 += __shfl_xor(l1,32,64);
    l2 += __shfl_xor(l2,16,64); l2 += __shfl_xor(l2,32,64);
    if (lg==0){ psum[wave][cs*16+lr] = l1; psq[wave][cs*16+lr] = l2; }
  }
  __syncthreads();
  if (tid < 128){
    float t1 = psum[0][tid]+psum[1][tid]+psum[2][tid]+psum[3][tid];
    float t2 = psq[0][tid]+psq[1][tid]+psq[2][tid]+psq[3][tid];
    part[tid*512 + blockIdx.x] = t1;
    part[65536 + tid*512 + blockIdx.x] = t2;
  }
}

// ---------------- k_bnred: per-channel reduction -> BN scale/shift ----------------
__global__ __launch_bounds__(64) void k_bnred(const float* part, const float* gamma, const float* beta, float* bnstat){
  int c = blockIdx.x, t = threadIdx.x;
  float s=0.f, q=0.f;
  for (int i=t; i<512; i+=64){ s += part[c*512+i]; q += part[65536 + c*512+i]; }
  #pragma unroll
  for (int m=1; m<64; m<<=1){ s += __shfl_xor(s,m,64); q += __shfl_xor(q,m,64); }
  if (t==0){
    float mean = s * (1.f/(float)NS);
    float var  = q * (1.f/(float)NS) - mean*mean;
    float rstd = rsqrtf(var + 1e-5f);
    float sc = gamma[c]*rstd;
    bnstat[c] = sc;
    bnstat[128+c] = beta[c] - mean*sc;
  }
}

// ---------------- k_final: out = relu(y*scale + shift) + fsa ----------------
__global__ __launch_bounds__(256) void k_final(const unsigned short* ybuf, const float* fsa, const float* bnstat,
                                               float* out){
  long i0 = ((long)blockIdx.x*256 + threadIdx.x)*8;
  int c0 = (int)(i0 & (ND-1));
  bf16x8 yv = *(const bf16x8*)(ybuf + i0);
  f32x4 f0 = *(const f32x4*)(fsa + i0);
  f32x4 f1 = *(const f32x4*)(fsa + i0 + 4);
  f32x4 o0, o1;
  #pragma unroll
  for (int j=0;j<8;j++){
    int c = c0 + j;
    float v = bf2f((unsigned short)yv[j]) * bnstat[c] + bnstat[128+c];
    v = v > 0.f ? v : 0.f;
    float add = (j<4) ? f0[j] : f1[j-4];
    if (j<4) o0[j] = v + add; else o1[j-4] = v + add;
  }
  *(f32x4*)(out + i0) = o0;
  *(f32x4*)(out + i0 + 4) = o1;
}

extern "C" void kernel_launch(void* const* d_in, const int* in_sizes, int n_in,
                              void* d_out, int out_size, void* d_ws, size_t ws_size,
                              hipStream_t stream){
  const float* f_in  = (const float*)d_in[0];
  const float* w_q   = (const float*)d_in[1];
  const float* b_q   = (const float*)d_in[2];
  const float* w_k   = (const float*)d_in[3];
  const float* b_k   = (const float*)d_in[4];
  const float* w_v   = (const float*)d_in[5];
  const float* b_v   = (const float*)d_in[6];
  const float* w_l   = (const float*)d_in[7];
  const float* b_l   = (const float*)d_in[8];
  const float* gamma = (const float*)d_in[9];
  const float* beta  = (const float*)d_in[10];
  float* out = (float*)d_out;
  char* ws = (char*)d_ws;

  unsigned short* wbq = (unsigned short*)(ws + 0);
  unsigned short* wbk = (unsigned short*)(ws + 8192);
  unsigned short* wbv = (unsigned short*)(ws + 16384);
  unsigned short* wbl = (unsigned short*)(ws + 49152);
  unsigned short* Qb  = (unsigned short*)(ws + 81920);
  unsigned short* Kb  = (unsigned short*)(ws + 2179072);
  unsigned short* Vb  = (unsigned short*)(ws + 4276224);
  unsigned short* VT  = (unsigned short*)(ws + 12795904);
  float*          fsa = (float*)(ws + 22233088);
  unsigned short* ybuf= (unsigned short*)(ws + 39010304);
  float*          part= (float*)(ws + 47398912);
  float*          bnst= (float*)(ws + 47923200);

  k_prep  <<<160, 256, 0, stream>>>(w_q, w_k, w_v, w_l, wbq, wbk, wbv, wbl);
  k_qkv   <<<512, 256, 0, stream>>>(f_in, wbq, wbk, wbv, b_q, b_k, b_v, Qb, Kb, Vb);
  k_csv   <<<512, 256, 0, stream>>>(Qb, Kb, Vb, VT);
  k_pv    <<<512, 256, 0, stream>>>(Qb, Kb, VT, fsa);
  k_lin   <<<512, 256, 0, stream>>>(f_in, fsa, wbl, b_l, ybuf, part);
  k_bnred <<<128, 64, 0, stream>>>(part, gamma, beta, bnst);
  k_final <<<2048,256, 0, stream>>>(ybuf, fsa, bnst, out);
}